// Round 2
// 842.276 us; speedup vs baseline: 1.1686x; 1.1686x over previous
//
#include <hip/hip_runtime.h>

#define M_DIM 4096
#define K_DIM 4096
#define N_DIM 16384

typedef float v4f __attribute__((ext_vector_type(4)));
typedef __attribute__((address_space(3))) unsigned char lds_uchar;

// ---------------------------------------------------------------------------
// Kernel 1: per-token dynamic quantization of x. (unchanged — verified)
// ---------------------------------------------------------------------------
__global__ __launch_bounds__(256) void quant_x_kernel(
    const float* __restrict__ x, unsigned char* __restrict__ xq,
    float* __restrict__ xs) {
  const int row = blockIdx.x;
  const int t = threadIdx.x;
  const float4* xr4 = (const float4*)(x + (size_t)row * K_DIM);

  float4 v[4];
  float am = 0.f;
#pragma unroll
  for (int i = 0; i < 4; ++i) {
    v[i] = xr4[t + 256 * i];
    am = fmaxf(am, fmaxf(fmaxf(fabsf(v[i].x), fabsf(v[i].y)),
                         fmaxf(fabsf(v[i].z), fabsf(v[i].w))));
  }
#pragma unroll
  for (int off = 32; off > 0; off >>= 1)
    am = fmaxf(am, __shfl_xor(am, off, 64));
  __shared__ float red[4];
  if ((t & 63) == 0) red[t >> 6] = am;
  __syncthreads();
  am = fmaxf(fmaxf(red[0], red[1]), fmaxf(red[2], red[3]));

  const float scale = fmaxf(am / 448.0f, 1e-12f);
  if (t == 0) xs[row] = scale;

  uint32_t* out = (uint32_t*)(xq + (size_t)row * K_DIM);
#pragma unroll
  for (int i = 0; i < 4; ++i) {
    float a0 = v[i].x / scale, a1 = v[i].y / scale;
    float a2 = v[i].z / scale, a3 = v[i].w / scale;
    uint32_t p = __builtin_amdgcn_cvt_pk_fp8_f32(a0, a1, 0, false);
    p = __builtin_amdgcn_cvt_pk_fp8_f32(a2, a3, p, true);
    out[t + 256 * i] = p;
  }
}

// ---------------------------------------------------------------------------
// Kernel 2: repack weight fp32 codes -> fp8 bytes. (unchanged — verified)
// ---------------------------------------------------------------------------
__global__ __launch_bounds__(256) void quant_w_kernel(
    const float4* __restrict__ w, uint32_t* __restrict__ wq) {
  const int i = blockIdx.x * 256 + threadIdx.x;
  float4 v = w[i];
  uint32_t p = __builtin_amdgcn_cvt_pk_fp8_f32(v.x, v.y, 0, false);
  p = __builtin_amdgcn_cvt_pk_fp8_f32(v.z, v.w, p, true);
  wq[i] = p;
}

// ---------------------------------------------------------------------------
// Kernel 3: fp8 GEMM — 256x256 tile, 8-wave, 4-phase/K-tile schedule with
// counted vmcnt (T3+T4), XOR-swizzled LDS (T2), setprio around MFMA (T5),
// triple-buffered LDS (prefetch distance 2 K-tiles), XCD-aware block swizzle.
// ds_read addressing now goes through an address_space(3) pointer (same cast
// the proven async_copy16 uses) — no hand-truncated flat address.
// ---------------------------------------------------------------------------
__device__ __forceinline__ void async_copy16(const void* g, void* l) {
  __builtin_amdgcn_global_load_lds(
      (const __attribute__((address_space(1))) void*)g,
      (__attribute__((address_space(3))) void*)l, 16, 0, 0);
}

__device__ __forceinline__ long long lds_read_b64(const lds_uchar* p) {
  long long d;
  asm volatile("ds_read_b64 %0, %1" : "=v"(d) : "v"(p));
  return d;
}

#define MF(a, b, c) __builtin_amdgcn_mfma_f32_16x16x32_fp8_fp8(a, b, c, 0, 0, 0)

#define AOFF(i, ks) ((ks) ? (aoff[i] ^ 32u) : aoff[i])
#define BOFF(j, ks) ((ks) ? (boff[j] ^ 32u) : boff[j])

// One phase: {ds_read frags | issue 1 stage load} -> barrier -> lgkmcnt(0) ->
// sched_barrier (rule #18) -> setprio(1) -> 16 MFMA -> setprio(0) -> TAIL ->
// barrier.  fb frags persist across the mh=1 phases.
#define PHASE(ks, mh, STAGE_STMT, TAIL_STMT)                            \
  {                                                                     \
    fa0 = lds_read_b64(bb + AOFF(4 * (mh) + 0, ks));                    \
    fa1 = lds_read_b64(bb + AOFF(4 * (mh) + 1, ks));                    \
    fa2 = lds_read_b64(bb + AOFF(4 * (mh) + 2, ks));                    \
    fa3 = lds_read_b64(bb + AOFF(4 * (mh) + 3, ks));                    \
    if ((mh) == 0) {                                                    \
      fb0 = lds_read_b64(bb + BOFF(0, ks));                             \
      fb1 = lds_read_b64(bb + BOFF(1, ks));                             \
      fb2 = lds_read_b64(bb + BOFF(2, ks));                             \
      fb3 = lds_read_b64(bb + BOFF(3, ks));                             \
    }                                                                   \
    STAGE_STMT;                                                         \
    __builtin_amdgcn_s_barrier();                                       \
    asm volatile("s_waitcnt lgkmcnt(0)");                               \
    __builtin_amdgcn_sched_barrier(0);                                  \
    __builtin_amdgcn_s_setprio(1);                                      \
    acc[4 * (mh) + 0][0] = MF(fa0, fb0, acc[4 * (mh) + 0][0]);          \
    acc[4 * (mh) + 0][1] = MF(fa0, fb1, acc[4 * (mh) + 0][1]);          \
    acc[4 * (mh) + 0][2] = MF(fa0, fb2, acc[4 * (mh) + 0][2]);          \
    acc[4 * (mh) + 0][3] = MF(fa0, fb3, acc[4 * (mh) + 0][3]);          \
    acc[4 * (mh) + 1][0] = MF(fa1, fb0, acc[4 * (mh) + 1][0]);          \
    acc[4 * (mh) + 1][1] = MF(fa1, fb1, acc[4 * (mh) + 1][1]);          \
    acc[4 * (mh) + 1][2] = MF(fa1, fb2, acc[4 * (mh) + 1][2]);          \
    acc[4 * (mh) + 1][3] = MF(fa1, fb3, acc[4 * (mh) + 1][3]);          \
    acc[4 * (mh) + 2][0] = MF(fa2, fb0, acc[4 * (mh) + 2][0]);          \
    acc[4 * (mh) + 2][1] = MF(fa2, fb1, acc[4 * (mh) + 2][1]);          \
    acc[4 * (mh) + 2][2] = MF(fa2, fb2, acc[4 * (mh) + 2][2]);          \
    acc[4 * (mh) + 2][3] = MF(fa2, fb3, acc[4 * (mh) + 2][3]);          \
    acc[4 * (mh) + 3][0] = MF(fa3, fb0, acc[4 * (mh) + 3][0]);          \
    acc[4 * (mh) + 3][1] = MF(fa3, fb1, acc[4 * (mh) + 3][1]);          \
    acc[4 * (mh) + 3][2] = MF(fa3, fb2, acc[4 * (mh) + 3][2]);          \
    acc[4 * (mh) + 3][3] = MF(fa3, fb3, acc[4 * (mh) + 3][3]);          \
    __builtin_amdgcn_sched_barrier(0);                                  \
    __builtin_amdgcn_s_setprio(0);                                      \
    TAIL_STMT;                                                          \
    __builtin_amdgcn_s_barrier();                                       \
  }

// One K-tile = 4 phases (ks, mh).  Stage loads for K-tile t+2 are spread
// one-per-phase; the counted vmcnt lives in the TAIL of the last phase.
#define TILE(DO_STAGE, TAIL_STMT)                                       \
  PHASE(0, 0, if (DO_STAGE) async_copy16(gA0 + kst, sd), (void)0)       \
  PHASE(0, 1, if (DO_STAGE) async_copy16(gA1 + kst, sd + 8192), (void)0)\
  PHASE(1, 0, if (DO_STAGE) async_copy16(gB0 + kst, sd + 16384), (void)0)\
  PHASE(1, 1, if (DO_STAGE) async_copy16(gB1 + kst, sd + 24576), TAIL_STMT)

__global__ __launch_bounds__(512, 2) void gemm_fp8_kernel(
    const unsigned char* __restrict__ Aq,  // [M,K] fp8
    const unsigned char* __restrict__ Bq,  // [N,K] fp8
    const float* __restrict__ xs,          // [M]
    const float* __restrict__ wscale,      // [N]
    const float* __restrict__ bias,        // [N]
    float* __restrict__ y) {               // [M,N]
  constexpr int BK = 64;
  __shared__ __align__(16) unsigned char smem[3 * 32768];  // 96 KiB, 3 bufs

  const int tid = threadIdx.x;

  // bijective XCD swizzle: 1024 blocks, 8 XCDs -> each XCD gets 128
  // contiguous output tiles (2 full grid rows -> A-panel reuse in its L2).
  const int id = blockIdx.x;
  const int sw = (id & 7) * 128 + (id >> 3);
  const int bm = (sw >> 6) * 256;  // 16 rows of tiles
  const int bn = (sw & 63) * 256;  // 64 cols of tiles

  // --- staging geometry: linear LDS dst (global_load_lds constraint),
  //     pre-swizzled GLOBAL source chunk: LDS[row][c] = G[row][c ^ g(row)],
  //     g(row) = (row>>1)&3  (identical to the verified 128^2 kernel) ---
  const int srow = tid >> 2;  // 0..127 (row within half-tile)
  const unsigned scol = (unsigned)(((tid & 3) ^ ((srow >> 1) & 3)) * 16);
  const unsigned char* gA0 = Aq + (size_t)(bm + srow) * K_DIM + scol;
  const unsigned char* gA1 = gA0 + (size_t)128 * K_DIM;
  const unsigned char* gB0 = Bq + (size_t)(bn + srow) * K_DIM + scol;
  const unsigned char* gB1 = gB0 + (size_t)128 * K_DIM;

  // --- wave/lane geometry: 8 waves as 2(M) x 4(N); per-wave 128x64 out ---
  const int lane = tid & 63;
  const int w = tid >> 6;
  const int wmo = (w >> 2) * 128;
  const int wno = (w & 3) * 64;
  const int lrow = lane & 15;  // A-row / B-col within fragment
  const int lq = lane >> 4;    // k-quad: k-base lq*8, C-row base lq*4
  const unsigned xm = (unsigned)(((lrow >> 1) & 3) << 4);
  const unsigned koff0 = ((unsigned)(lq * 8)) ^ xm;

  unsigned aoff[8], boff[4];
#pragma unroll
  for (int i = 0; i < 8; ++i)
    aoff[i] = (unsigned)((wmo + i * 16 + lrow) * 64) + koff0;
#pragma unroll
  for (int j = 0; j < 4; ++j)
    boff[j] = 16384u + (unsigned)((wno + j * 16 + lrow) * 64) + koff0;

  v4f acc[8][4];
#pragma unroll
  for (int i = 0; i < 8; ++i)
#pragma unroll
    for (int j = 0; j < 4; ++j) acc[i][j] = {0.f, 0.f, 0.f, 0.f};

  long long fa0, fa1, fa2, fa3;
  long long fb0 = 0, fb1 = 0, fb2 = 0, fb3 = 0;

  // --- prologue: stage K-tiles 0 and 1 into buffers 0 and 1 ---
  {
    unsigned char* s0 = smem + tid * 16;
    async_copy16(gA0, s0);
    async_copy16(gA1, s0 + 8192);
    async_copy16(gB0, s0 + 16384);
    async_copy16(gB1, s0 + 24576);
    unsigned char* s1 = s0 + 32768;
    async_copy16(gA0 + BK, s1);
    async_copy16(gA1 + BK, s1 + 8192);
    async_copy16(gB0 + BK, s1 + 16384);
    async_copy16(gB1 + BK, s1 + 24576);
  }
  asm volatile("s_waitcnt vmcnt(4)");  // tile 0 landed; tile 1 in flight
  __builtin_amdgcn_s_barrier();

  // --- main loop: 64 K-tiles; tiles 0..61 stage t+2 and wait vmcnt(4);
  //     tile 62 drains (vmcnt 0); tile 63 computes only. ---
  int cur = 0, stg = 2;
  for (int t = 0; t < 62; ++t) {
    const lds_uchar* bb = (const lds_uchar*)(smem + cur * 32768);
    unsigned char* sd = smem + stg * 32768 + tid * 16;
    const int kst = (t + 2) * BK;
    TILE(1, asm volatile("s_waitcnt vmcnt(4)"))
    cur = (cur == 2) ? 0 : cur + 1;
    stg = (stg == 2) ? 0 : stg + 1;
  }
  {
    const lds_uchar* bb = (const lds_uchar*)(smem + cur * 32768);
    unsigned char* sd = smem + tid * 16;  // unused
    const int kst = 0;                    // unused
    TILE(0, asm volatile("s_waitcnt vmcnt(0)"))
    cur = (cur == 2) ? 0 : cur + 1;
  }
  {
    const lds_uchar* bb = (const lds_uchar*)(smem + cur * 32768);
    unsigned char* sd = smem + tid * 16;  // unused
    const int kst = 0;                    // unused
    TILE(0, (void)0)
  }

  // --- epilogue: C/D layout col=lane&15, row=(lane>>4)*4+reg ---
  const int bmw = bm + wmo;
  const int bnw = bn + wno;
  float xsv[8][4];
#pragma unroll
  for (int i = 0; i < 8; ++i)
#pragma unroll
    for (int r = 0; r < 4; ++r)
      xsv[i][r] = xs[bmw + i * 16 + lq * 4 + r];

#pragma unroll
  for (int j = 0; j < 4; ++j) {
    const int col = bnw + j * 16 + lrow;
    const float wsc = wscale[col];
    const float bv = bias[col];
#pragma unroll
    for (int i = 0; i < 8; ++i) {
      const int row0 = bmw + i * 16 + lq * 4;
#pragma unroll
      for (int r = 0; r < 4; ++r)
        y[(size_t)(row0 + r) * N_DIM + col] =
            acc[i][j][r] * xsv[i][r] * wsc + bv;
    }
  }
}

// ---------------------------------------------------------------------------
extern "C" void kernel_launch(void* const* d_in, const int* in_sizes, int n_in,
                              void* d_out, int out_size, void* d_ws,
                              size_t ws_size, hipStream_t stream) {
  const float* x = (const float*)d_in[0];       // [M,K]
  const float* w = (const float*)d_in[1];       // [N,K] fp8 codes in fp32
  const float* wscale = (const float*)d_in[2];  // [N,1]
  const float* bias = (const float*)d_in[3];    // [N]
  float* y = (float*)d_out;                     // [M,N]

  unsigned char* xq = (unsigned char*)d_ws;                  // 16 MiB
  unsigned char* wq = xq + (size_t)M_DIM * K_DIM;            // 64 MiB
  float* xs = (float*)(wq + (size_t)N_DIM * K_DIM);          // 16 KiB

  quant_x_kernel<<<M_DIM, 256, 0, stream>>>(x, xq, xs);
  quant_w_kernel<<<((size_t)N_DIM * K_DIM / 4) / 256, 256, 0, stream>>>(
      (const float4*)w, (uint32_t*)wq);
  gemm_fp8_kernel<<<(M_DIM / 256) * (N_DIM / 256), 512, 0, stream>>>(
      xq, wq, xs, wscale, bias, y);
}

// Round 3
// 837.186 us; speedup vs baseline: 1.1757x; 1.0061x over previous
//
#include <hip/hip_runtime.h>

#define M_DIM 4096
#define K_DIM 4096
#define N_DIM 16384

typedef float v4f __attribute__((ext_vector_type(4)));
typedef __attribute__((address_space(3))) unsigned char lds_uchar;

// ---------------------------------------------------------------------------
// Kernel 1: per-token dynamic quantization of x. (unchanged — verified)
// ---------------------------------------------------------------------------
__global__ __launch_bounds__(256) void quant_x_kernel(
    const float* __restrict__ x, unsigned char* __restrict__ xq,
    float* __restrict__ xs) {
  const int row = blockIdx.x;
  const int t = threadIdx.x;
  const float4* xr4 = (const float4*)(x + (size_t)row * K_DIM);

  float4 v[4];
  float am = 0.f;
#pragma unroll
  for (int i = 0; i < 4; ++i) {
    v[i] = xr4[t + 256 * i];
    am = fmaxf(am, fmaxf(fmaxf(fabsf(v[i].x), fabsf(v[i].y)),
                         fmaxf(fabsf(v[i].z), fabsf(v[i].w))));
  }
#pragma unroll
  for (int off = 32; off > 0; off >>= 1)
    am = fmaxf(am, __shfl_xor(am, off, 64));
  __shared__ float red[4];
  if ((t & 63) == 0) red[t >> 6] = am;
  __syncthreads();
  am = fmaxf(fmaxf(red[0], red[1]), fmaxf(red[2], red[3]));

  const float scale = fmaxf(am / 448.0f, 1e-12f);
  if (t == 0) xs[row] = scale;

  uint32_t* out = (uint32_t*)(xq + (size_t)row * K_DIM);
#pragma unroll
  for (int i = 0; i < 4; ++i) {
    float a0 = v[i].x / scale, a1 = v[i].y / scale;
    float a2 = v[i].z / scale, a3 = v[i].w / scale;
    uint32_t p = __builtin_amdgcn_cvt_pk_fp8_f32(a0, a1, 0, false);
    p = __builtin_amdgcn_cvt_pk_fp8_f32(a2, a3, p, true);
    out[t + 256 * i] = p;
  }
}

// ---------------------------------------------------------------------------
// Kernel 2: repack weight fp32 codes -> fp8 bytes. (unchanged — verified)
// ---------------------------------------------------------------------------
__global__ __launch_bounds__(256) void quant_w_kernel(
    const float4* __restrict__ w, uint32_t* __restrict__ wq) {
  const int i = blockIdx.x * 256 + threadIdx.x;
  float4 v = w[i];
  uint32_t p = __builtin_amdgcn_cvt_pk_fp8_f32(v.x, v.y, 0, false);
  p = __builtin_amdgcn_cvt_pk_fp8_f32(v.z, v.w, p, true);
  wq[i] = p;
}

// ---------------------------------------------------------------------------
// Kernel 3: fp8 GEMM — 256x256 tile, 8-wave, 4-phase/K-tile, triple-buffered
// LDS (distance-2, counted vmcnt), XOR-swizzled LDS, setprio around MFMA.
// NEW this round: one-phase fragment READ-AHEAD with counted lgkmcnt(4/8) —
// each phase issues the NEXT phase's ds_reads, then waits only for the older
// group before its MFMA cluster, hiding the LDS drain under the MFMAs.
// ---------------------------------------------------------------------------
__device__ __forceinline__ void async_copy16(const void* g, void* l) {
  __builtin_amdgcn_global_load_lds(
      (const __attribute__((address_space(1))) void*)g,
      (__attribute__((address_space(3))) void*)l, 16, 0, 0);
}

__device__ __forceinline__ long long lds_read_b64(const lds_uchar* p) {
  long long d;
  asm volatile("ds_read_b64 %0, %1" : "=v"(d) : "v"(p));
  return d;
}

#define MF(a, b, c) __builtin_amdgcn_mfma_f32_16x16x32_fp8_fp8(a, b, c, 0, 0, 0)

#define MFMA16(R, A0, A1, A2, A3, B)                     \
  acc[(R) + 0][0] = MF(A0, B##0, acc[(R) + 0][0]);       \
  acc[(R) + 0][1] = MF(A0, B##1, acc[(R) + 0][1]);       \
  acc[(R) + 0][2] = MF(A0, B##2, acc[(R) + 0][2]);       \
  acc[(R) + 0][3] = MF(A0, B##3, acc[(R) + 0][3]);       \
  acc[(R) + 1][0] = MF(A1, B##0, acc[(R) + 1][0]);       \
  acc[(R) + 1][1] = MF(A1, B##1, acc[(R) + 1][1]);       \
  acc[(R) + 1][2] = MF(A1, B##2, acc[(R) + 1][2]);       \
  acc[(R) + 1][3] = MF(A1, B##3, acc[(R) + 1][3]);       \
  acc[(R) + 2][0] = MF(A2, B##0, acc[(R) + 2][0]);       \
  acc[(R) + 2][1] = MF(A2, B##1, acc[(R) + 2][1]);       \
  acc[(R) + 2][2] = MF(A2, B##2, acc[(R) + 2][2]);       \
  acc[(R) + 2][3] = MF(A2, B##3, acc[(R) + 2][3]);       \
  acc[(R) + 3][0] = MF(A3, B##0, acc[(R) + 3][0]);       \
  acc[(R) + 3][1] = MF(A3, B##1, acc[(R) + 3][1]);       \
  acc[(R) + 3][2] = MF(A3, B##2, acc[(R) + 3][2]);       \
  acc[(R) + 3][3] = MF(A3, B##3, acc[(R) + 3][3])

// barrier -> counted lgkm wait (older read-group only) -> fence -> MFMA ->
// fence -> TAIL (counted vmcnt) -> barrier
#define PH_CORE(LGKMSTR, R, A0, A1, A2, A3, B, TAIL)     \
  __builtin_amdgcn_s_barrier();                          \
  asm volatile("s_waitcnt lgkmcnt(" LGKMSTR ")");        \
  __builtin_amdgcn_sched_barrier(0);                     \
  __builtin_amdgcn_s_setprio(1);                         \
  MFMA16(R, A0, A1, A2, A3, B);                          \
  __builtin_amdgcn_sched_barrier(0);                     \
  __builtin_amdgcn_s_setprio(0);                         \
  TAIL;                                                  \
  __builtin_amdgcn_s_barrier();

// One K-tile = 4 phases. Each phase issues the NEXT phase's fragment reads
// (A ping-pong sets; B per-ks sets), one staging load, then PH_CORE.
// P2's TAIL carries the per-tile counted vmcnt (tile t+1 residency for P3's
// cross-tile read-ahead from bufN).
#define TILE4(S, P2TAIL, DO_NEXT, P3LGKM)                \
  /* P0: issue A(4-7,ks0); consume Aset0 + Bks0 */       \
  a1_0 = lds_read_b64(bufC + aoff[4]);                   \
  a1_1 = lds_read_b64(bufC + aoff[5]);                   \
  a1_2 = lds_read_b64(bufC + aoff[6]);                   \
  a1_3 = lds_read_b64(bufC + aoff[7]);                   \
  if (S) async_copy16(gA0 + kst, sd);                    \
  PH_CORE("4", 0, a0_0, a0_1, a0_2, a0_3, b0_, ;)        \
  /* P1: issue A(0-3,ks1)+B(ks1); consume Aset1 + Bks0 */\
  a0_0 = lds_read_b64(bufC + (aoff[0] ^ 32u));           \
  a0_1 = lds_read_b64(bufC + (aoff[1] ^ 32u));           \
  a0_2 = lds_read_b64(bufC + (aoff[2] ^ 32u));           \
  a0_3 = lds_read_b64(bufC + (aoff[3] ^ 32u));           \
  b1_0 = lds_read_b64(bufC + (boff[0] ^ 32u));           \
  b1_1 = lds_read_b64(bufC + (boff[1] ^ 32u));           \
  b1_2 = lds_read_b64(bufC + (boff[2] ^ 32u));           \
  b1_3 = lds_read_b64(bufC + (boff[3] ^ 32u));           \
  if (S) async_copy16(gA1 + kst, sd + 8192);             \
  PH_CORE("8", 4, a1_0, a1_1, a1_2, a1_3, b0_, ;)        \
  /* P2: issue A(4-7,ks1); consume Aset0 + Bks1 */       \
  a1_0 = lds_read_b64(bufC + (aoff[4] ^ 32u));           \
  a1_1 = lds_read_b64(bufC + (aoff[5] ^ 32u));           \
  a1_2 = lds_read_b64(bufC + (aoff[6] ^ 32u));           \
  a1_3 = lds_read_b64(bufC + (aoff[7] ^ 32u));           \
  if (S) async_copy16(gB0 + kst, sd + 16384);            \
  PH_CORE("4", 0, a0_0, a0_1, a0_2, a0_3, b1_, P2TAIL)   \
  /* P3: issue NEXT tile A(0-3,ks0)+B(ks0); consume Aset1 + Bks1 */ \
  if (DO_NEXT) {                                         \
    a0_0 = lds_read_b64(bufN + aoff[0]);                 \
    a0_1 = lds_read_b64(bufN + aoff[1]);                 \
    a0_2 = lds_read_b64(bufN + aoff[2]);                 \
    a0_3 = lds_read_b64(bufN + aoff[3]);                 \
    b0_0 = lds_read_b64(bufN + boff[0]);                 \
    b0_1 = lds_read_b64(bufN + boff[1]);                 \
    b0_2 = lds_read_b64(bufN + boff[2]);                 \
    b0_3 = lds_read_b64(bufN + boff[3]);                 \
  }                                                      \
  if (S) async_copy16(gB1 + kst, sd + 24576);            \
  PH_CORE(P3LGKM, 4, a1_0, a1_1, a1_2, a1_3, b1_, ;)

__global__ __launch_bounds__(512, 2) void gemm_fp8_kernel(
    const unsigned char* __restrict__ Aq,  // [M,K] fp8
    const unsigned char* __restrict__ Bq,  // [N,K] fp8
    const float* __restrict__ xs,          // [M]
    const float* __restrict__ wscale,      // [N]
    const float* __restrict__ bias,        // [N]
    float* __restrict__ y) {               // [M,N]
  constexpr int BK = 64;
  __shared__ __align__(16) unsigned char smem[3 * 32768];  // 96 KiB, 3 bufs

  const int tid = threadIdx.x;

  // bijective XCD swizzle: 1024 blocks, 8 XCDs -> 128 contiguous tiles each.
  const int id = blockIdx.x;
  const int sw = (id & 7) * 128 + (id >> 3);
  const int bm = (sw >> 6) * 256;
  const int bn = (sw & 63) * 256;

  // staging: linear LDS dst, pre-swizzled GLOBAL source chunk,
  // g(row) = (row>>1)&3  (verified swizzle).
  const int srow = tid >> 2;
  const unsigned scol = (unsigned)(((tid & 3) ^ ((srow >> 1) & 3)) * 16);
  const unsigned char* gA0 = Aq + (size_t)(bm + srow) * K_DIM + scol;
  const unsigned char* gA1 = gA0 + (size_t)128 * K_DIM;
  const unsigned char* gB0 = Bq + (size_t)(bn + srow) * K_DIM + scol;
  const unsigned char* gB1 = gB0 + (size_t)128 * K_DIM;

  // wave/lane geometry: 8 waves as 2(M) x 4(N); per-wave 128x64 out.
  const int lane = tid & 63;
  const int w = tid >> 6;
  const int wmo = (w >> 2) * 128;
  const int wno = (w & 3) * 64;
  const int lrow = lane & 15;
  const int lq = lane >> 4;
  const unsigned xm = (unsigned)(((lrow >> 1) & 3) << 4);
  const unsigned koff0 = ((unsigned)(lq * 8)) ^ xm;

  unsigned aoff[8], boff[4];
#pragma unroll
  for (int i = 0; i < 8; ++i)
    aoff[i] = (unsigned)((wmo + i * 16 + lrow) * 64) + koff0;
#pragma unroll
  for (int j = 0; j < 4; ++j)
    boff[j] = 16384u + (unsigned)((wno + j * 16 + lrow) * 64) + koff0;

  v4f acc[8][4];
#pragma unroll
  for (int i = 0; i < 8; ++i)
#pragma unroll
    for (int j = 0; j < 4; ++j) acc[i][j] = {0.f, 0.f, 0.f, 0.f};

  long long a0_0, a0_1, a0_2, a0_3;  // Aset0: consumed by P0/P2
  long long a1_0, a1_1, a1_2, a1_3;  // Aset1: consumed by P1/P3
  long long b0_0, b0_1, b0_2, b0_3;  // B ks0: consumed by P0/P1
  long long b1_0, b1_1, b1_2, b1_3;  // B ks1: consumed by P2/P3

  // prologue: stage K-tiles 0 and 1 into buffers 0 and 1
  {
    unsigned char* s0 = smem + tid * 16;
    async_copy16(gA0, s0);
    async_copy16(gA1, s0 + 8192);
    async_copy16(gB0, s0 + 16384);
    async_copy16(gB1, s0 + 24576);
    unsigned char* s1 = s0 + 32768;
    async_copy16(gA0 + BK, s1);
    async_copy16(gA1 + BK, s1 + 8192);
    async_copy16(gB0 + BK, s1 + 16384);
    async_copy16(gB1 + BK, s1 + 24576);
  }
  asm volatile("s_waitcnt vmcnt(4)");  // tile 0 landed; tile 1 in flight
  __builtin_amdgcn_s_barrier();

  // pre-read tile-0 P0 fragments (A 0-3 ks0 + B ks0) from buffer 0
  {
    const lds_uchar* b0p = (const lds_uchar*)smem;
    a0_0 = lds_read_b64(b0p + aoff[0]);
    a0_1 = lds_read_b64(b0p + aoff[1]);
    a0_2 = lds_read_b64(b0p + aoff[2]);
    a0_3 = lds_read_b64(b0p + aoff[3]);
    b0_0 = lds_read_b64(b0p + boff[0]);
    b0_1 = lds_read_b64(b0p + boff[1]);
    b0_2 = lds_read_b64(b0p + boff[2]);
    b0_3 = lds_read_b64(b0p + boff[3]);
  }

  // main loop: tiles 0..61 stage t+2 (vmcnt(3) at P2-end); 62 drains
  // (vmcnt(0) at P2-end); 63 computes only, no read-ahead at its P3.
  int cur = 0, stg = 2;
  for (int t = 0; t < 62; ++t) {
    const int nxt = (cur == 2) ? 0 : cur + 1;
    const lds_uchar* bufC = (const lds_uchar*)(smem + cur * 32768);
    const lds_uchar* bufN = (const lds_uchar*)(smem + nxt * 32768);
    unsigned char* sd = smem + stg * 32768 + tid * 16;
    const int kst = (t + 2) * BK;
    TILE4(1, asm volatile("s_waitcnt vmcnt(3)"), 1, "8")
    cur = nxt;
    stg = (stg == 2) ? 0 : stg + 1;
  }
  {  // t = 62: no staging; drain so tile 63 is resident for P3 read-ahead
    const int nxt = (cur == 2) ? 0 : cur + 1;
    const lds_uchar* bufC = (const lds_uchar*)(smem + cur * 32768);
    const lds_uchar* bufN = (const lds_uchar*)(smem + nxt * 32768);
    unsigned char* sd = smem + tid * 16;  // unused
    const int kst = 0;                    // unused
    TILE4(0, asm volatile("s_waitcnt vmcnt(0)"), 1, "8")
    cur = nxt;
  }
  {  // t = 63: final tile, no read-ahead
    const lds_uchar* bufC = (const lds_uchar*)(smem + cur * 32768);
    const lds_uchar* bufN = bufC;         // unused
    unsigned char* sd = smem + tid * 16;  // unused
    const int kst = 0;                    // unused
    TILE4(0, ;, 0, "0")
  }

  // epilogue: C/D layout col=lane&15, row=(lane>>4)*4+reg
  const int bmw = bm + wmo;
  const int bnw = bn + wno;
  float xsv[8][4];
#pragma unroll
  for (int i = 0; i < 8; ++i)
#pragma unroll
    for (int r = 0; r < 4; ++r)
      xsv[i][r] = xs[bmw + i * 16 + lq * 4 + r];

#pragma unroll
  for (int j = 0; j < 4; ++j) {
    const int col = bnw + j * 16 + lrow;
    const float wsc = wscale[col];
    const float bv = bias[col];
#pragma unroll
    for (int i = 0; i < 8; ++i) {
      const int row0 = bmw + i * 16 + lq * 4;
#pragma unroll
      for (int r = 0; r < 4; ++r)
        y[(size_t)(row0 + r) * N_DIM + col] =
            acc[i][j][r] * xsv[i][r] * wsc + bv;
    }
  }
}

// ---------------------------------------------------------------------------
extern "C" void kernel_launch(void* const* d_in, const int* in_sizes, int n_in,
                              void* d_out, int out_size, void* d_ws,
                              size_t ws_size, hipStream_t stream) {
  const float* x = (const float*)d_in[0];       // [M,K]
  const float* w = (const float*)d_in[1];       // [N,K] fp8 codes in fp32
  const float* wscale = (const float*)d_in[2];  // [N,1]
  const float* bias = (const float*)d_in[3];    // [N]
  float* y = (float*)d_out;                     // [M,N]

  unsigned char* xq = (unsigned char*)d_ws;                  // 16 MiB
  unsigned char* wq = xq + (size_t)M_DIM * K_DIM;            // 64 MiB
  float* xs = (float*)(wq + (size_t)N_DIM * K_DIM);          // 16 KiB

  quant_x_kernel<<<M_DIM, 256, 0, stream>>>(x, xq, xs);
  quant_w_kernel<<<((size_t)N_DIM * K_DIM / 4) / 256, 256, 0, stream>>>(
      (const float4*)w, (uint32_t*)wq);
  gemm_fp8_kernel<<<(M_DIM / 256) * (N_DIM / 256), 512, 0, stream>>>(
      xq, wq, xs, wscale, bias, y);
}